// Round 5
// baseline (395.001 us; speedup 1.0000x reference)
//
#include <hip/hip_runtime.h>
#include <hip/hip_bf16.h>
#include <math.h>

#define T_TOK 2048
#define DM 768
#define DF 3072
#define NE 8

typedef __attribute__((ext_vector_type(4))) float f32x4;
typedef __attribute__((ext_vector_type(8))) short bf16x8;

static __device__ __forceinline__ ushort f2bf(float f) {
    union { float f; unsigned u; } x; x.f = f;
    unsigned r = x.u + 0x7fff + ((x.u >> 16) & 1);
    return (ushort)(r >> 16);
}
static __device__ __forceinline__ float bf2f(ushort u) {
    union { unsigned u; float f; } x; x.u = ((unsigned)u) << 16; return x.f;
}
static __device__ __forceinline__ unsigned pk2(float lo, float hi) {
    return (unsigned)f2bf(lo) | ((unsigned)f2bf(hi) << 16);
}

// ---------------- LN + router (top-2) ----------------
__global__ __launch_bounds__(256) void ln_router_kernel(
    const float* __restrict__ hs, const float* __restrict__ gamma,
    const float* __restrict__ beta, const float* __restrict__ rw,
    ushort* __restrict__ xbf, float* __restrict__ topw, int* __restrict__ topi,
    int* __restrict__ counts)
{
    int t = blockIdx.x;
    int tid = threadIdx.x;
    const float* row = hs + (size_t)t * DM;
    float v[3];
    v[0] = row[tid]; v[1] = row[tid + 256]; v[2] = row[tid + 512];
    float s  = v[0] + v[1] + v[2];
    float sq = v[0]*v[0] + v[1]*v[1] + v[2]*v[2];
    #pragma unroll
    for (int off = 32; off > 0; off >>= 1) {
        s  += __shfl_down(s, off);
        sq += __shfl_down(sq, off);
    }
    __shared__ float wsum[4], wsq[4];
    __shared__ float pl[4][8];
    int lane = tid & 63, wv = tid >> 6;
    if (lane == 0) { wsum[wv] = s; wsq[wv] = sq; }
    __syncthreads();
    float tot  = wsum[0] + wsum[1] + wsum[2] + wsum[3];
    float totq = wsq[0] + wsq[1] + wsq[2] + wsq[3];
    float mu = tot * (1.0f / 768.0f);
    float var = totq * (1.0f / 768.0f) - mu * mu;
    float rstd = rsqrtf(var + 1e-5f);

    float p[8];
    #pragma unroll
    for (int e = 0; e < 8; e++) p[e] = 0.f;
    #pragma unroll
    for (int i = 0; i < 3; i++) {
        int d = tid + i * 256;
        float yv = (v[i] - mu) * rstd * gamma[d] + beta[d];
        xbf[(size_t)t * DM + d] = f2bf(yv);
        const float* r8 = rw + (size_t)d * 8;
        #pragma unroll
        for (int e = 0; e < 8; e++) p[e] += yv * r8[e];
    }
    #pragma unroll
    for (int off = 32; off > 0; off >>= 1) {
        #pragma unroll
        for (int e = 0; e < 8; e++) p[e] += __shfl_down(p[e], off);
    }
    if (lane == 0) {
        #pragma unroll
        for (int e = 0; e < 8; e++) pl[wv][e] = p[e];
    }
    __syncthreads();
    if (tid == 0) {
        float lg[8];
        #pragma unroll
        for (int e = 0; e < 8; e++) lg[e] = pl[0][e] + pl[1][e] + pl[2][e] + pl[3][e];
        int i0 = 0; float l0 = lg[0];
        #pragma unroll
        for (int e = 1; e < 8; e++) if (lg[e] > l0) { l0 = lg[e]; i0 = e; }
        int i1 = -1; float l1 = -3.4e38f;
        #pragma unroll
        for (int e = 0; e < 8; e++) if (e != i0 && lg[e] > l1) { l1 = lg[e]; i1 = e; }
        float w0 = 1.0f / (1.0f + __expf(l1 - l0));
        topi[2 * t] = i0;  topi[2 * t + 1] = i1;
        topw[2 * t] = w0;  topw[2 * t + 1] = 1.0f - w0;
        atomicAdd(&counts[i0], 1);
        atomicAdd(&counts[i1], 1);
    }
}

// ---------------- bucket fill (offsets computed in-register) ----------------
__global__ __launch_bounds__(256) void bucket_kernel(
    const int* __restrict__ topi, int* __restrict__ ctl,
    int* __restrict__ bucket_tok, int* __restrict__ tok_slot)
{
    int t = blockIdx.x * 256 + threadIdx.x;
    if (t >= T_TOK) return;
    int offs[8]; int acc = 0;
    #pragma unroll
    for (int e = 0; e < 8; e++) { offs[e] = acc; acc += ctl[e]; }
    #pragma unroll
    for (int k = 0; k < 2; k++) {
        int e = topi[2 * t + k];
        int pos = atomicAdd(&ctl[16 + e], 1);
        int idx = offs[e] + pos;
        bucket_tok[idx] = t;
        tok_slot[2 * t + k] = idx;
    }
}

// ---------------- bucketed MFMA GEMM, fused fp32->bf16 convert, depth-2 pipeline ----------
// C[M,N] = A[M,K] * W[K,N];  A: [M][K] bf16;  W: fp32 [E][K][N].
// 128x128 tile, BK=32, 4 waves. 3-deep LDS buffers, loads issued 2 tiles ahead,
// counted vmcnt (never full drain mid-loop), raw s_barrier.
// A: global_load_lds, source k-chunk XOR-swizzled (reads become 2-way = free).
// B: fp32 global->reg->pk2->swizzled ds_write (u32 bf16-pairs [16][128]).
template<bool SILU, bool GATHER, int NT, int SPLITS>
__global__ __launch_bounds__(256) void moe_gemm(
    const ushort* __restrict__ A, const float* __restrict__ W,
    ushort* __restrict__ C, const int* __restrict__ ctl,
    const int* __restrict__ bucket_tok, int K, int N)
{
    int bid = blockIdx.x;
    int e = bid & 7;
    int j = bid >> 3;
    int mt = j & 15;
    int c = j >> 4;
    int nt = c % NT;
    int sk = c / NT;
    int cnt = ctl[e];
    if (mt * 128 >= cnt) return;
    int off = 0;
    #pragma unroll
    for (int q = 0; q < 8; q++) if (q < e) off += ctl[q];
    const int Ks = K / SPLITS;
    const int kbase = sk * Ks;

    __shared__ ushort Al[3][128 * 32];
    __shared__ unsigned Bl[3][16 * 128];

    int tid = threadIdx.x, lane = tid & 63, wv = tid >> 6;
    // A source chunk swizzle: dest slot s (=lane&3) gets source chunk s ^ x,
    // x = (row_in_stripe>>1)&3 = (lane>>3)&3.  Read applies same involution.
    int kchA = ((lane & 3) ^ ((lane >> 3) & 3)) * 8;

    const ushort* aptr[2];
    #pragma unroll
    for (int i = 0; i < 2; i++) {
        int r = i * 64 + wv * 16 + (lane >> 2);
        int gr = mt * 128 + r;
        if (gr >= cnt) gr = cnt - 1;
        if (GATHER) aptr[i] = A + (size_t)bucket_tok[off + gr] * K;
        else        aptr[i] = A + (size_t)(off + gr) * K;
    }

    const float* Wb = W + (size_t)e * ((size_t)K * N);
    int n0 = nt * 128;
    int rp_[2], cc_[2];
    #pragma unroll
    for (int ii = 0; ii < 2; ii++) {
        int item = wv * 128 + ii * 64 + lane;
        rp_[ii] = item >> 5;          // k-pair row 0..15
        cc_[ii] = item & 31;          // col chunk (4 u32)
    }

    f32x4 acc[4][4];
    #pragma unroll
    for (int m = 0; m < 4; m++)
        #pragma unroll
        for (int n = 0; n < 4; n++)
            acc[m][n] = (f32x4){0.f, 0.f, 0.f, 0.f};

    int wr = wv >> 1, wc = wv & 1;
    int l15 = lane & 15, kq = lane >> 4;
    int ldstA = (wv * 16) * 32 + lane * 8;
    int xk = (kq & 1) << 4;

    auto stageA = [&](int buf, int k0) {
        #pragma unroll
        for (int i = 0; i < 2; i++) {
            __builtin_amdgcn_global_load_lds(
                (const __attribute__((address_space(1))) void*)(aptr[i] + k0 + kchA),
                (__attribute__((address_space(3))) void*)(&Al[buf][i * 64 * 32 + ldstA]),
                16, 0, 0);
        }
    };
    auto bload = [&](float4 (&br)[2][2], int k0) {
        #pragma unroll
        for (int ii = 0; ii < 2; ii++) {
            const float* s = Wb + (size_t)(k0 + 2 * rp_[ii]) * N + n0 + 4 * cc_[ii];
            br[ii][0] = *(const float4*)s;
            br[ii][1] = *(const float4*)(s + N);
        }
    };
    auto bwrite = [&](float4 (&br)[2][2], int buf) {
        #pragma unroll
        for (int ii = 0; ii < 2; ii++) {
            uint4 r;
            r.x = pk2(br[ii][0].x, br[ii][1].x);
            r.y = pk2(br[ii][0].y, br[ii][1].y);
            r.z = pk2(br[ii][0].z, br[ii][1].z);
            r.w = pk2(br[ii][0].w, br[ii][1].w);
            *(uint4*)&Bl[buf][rp_[ii] * 128 + ((4 * cc_[ii]) ^ ((rp_[ii] & 7) << 2))] = r;
        }
    };
    auto compute = [&](int cur) {
        bf16x8 af[4], bfr[4];
        #pragma unroll
        for (int m = 0; m < 4; m++) {
            int row = wr * 64 + m * 16 + l15;
            af[m] = *(const bf16x8*)&Al[cur][row * 32 + ((kq ^ ((row >> 1) & 3)) << 3)];
        }
        const unsigned* Blc = &Bl[cur][0];
        #pragma unroll
        for (int n = 0; n < 4; n++) {
            int ncol = wc * 64 + n * 16 + l15;
            union { uint4 u; bf16x8 h; } cvu;
            cvu.u.x = Blc[(kq * 4 + 0) * 128 + (ncol ^ (xk | 0))];
            cvu.u.y = Blc[(kq * 4 + 1) * 128 + (ncol ^ (xk | 4))];
            cvu.u.z = Blc[(kq * 4 + 2) * 128 + (ncol ^ (xk | 8))];
            cvu.u.w = Blc[(kq * 4 + 3) * 128 + (ncol ^ (xk | 12))];
            bfr[n] = cvu.h;
        }
        __builtin_amdgcn_s_setprio(1);
        #pragma unroll
        for (int m = 0; m < 4; m++)
            #pragma unroll
            for (int n = 0; n < 4; n++)
                acc[m][n] = __builtin_amdgcn_mfma_f32_16x16x32_bf16(af[m], bfr[n], acc[m][n], 0, 0, 0);
        __builtin_amdgcn_s_setprio(0);
    };

    #define FENCE asm volatile("" ::: "memory")
    float4 brg0[2][2], brg1[2][2];
    const int nk = Ks >> 5;   // always even (>=2) for our launches

    // prologue: tiles 0,1 in flight (pinned order: B0, A0, B1, A1)
    bload(brg0, kbase); FENCE;
    stageA(0, kbase); FENCE;
    bload(brg1, kbase + 32); FENCE;
    stageA(1, kbase + 32); FENCE;
    bwrite(brg0, 0);                                   // compiler waits brg0 loads
    asm volatile("s_waitcnt vmcnt(6)" ::: "memory");   // drain A0 (leaves B1,A1)
    asm volatile("s_waitcnt lgkmcnt(0)" ::: "memory");
    __builtin_amdgcn_s_barrier();

    // iter t: prefetch tile t+2 (into BLD regs), compute tile t, write tile t+1 (from BWR regs)
    #define BODY(T, BLD, BWR) { \
        int t_ = (T); \
        bool more2 = (t_ + 2 < nk); \
        if (more2) { \
            bload(BLD, kbase + (t_ + 2) * 32); FENCE; \
            stageA((t_ + 2) % 3, kbase + (t_ + 2) * 32); FENCE; \
        } \
        compute(t_ % 3); \
        if (t_ + 1 < nk) { \
            bwrite(BWR, (t_ + 1) % 3); \
            if (more2) asm volatile("s_waitcnt vmcnt(6)" ::: "memory"); \
            else       asm volatile("s_waitcnt vmcnt(0)" ::: "memory"); \
            asm volatile("s_waitcnt lgkmcnt(0)" ::: "memory"); \
            __builtin_amdgcn_s_barrier(); \
        } \
    }

    for (int t = 0; t < nk; t += 2) {
        BODY(t, brg0, brg1);
        BODY(t + 1, brg1, brg0);
    }
    #undef BODY
    #undef FENCE

    // epilogue: row = (lane>>4)*4 + jj, col = lane&15
    #pragma unroll
    for (int m = 0; m < 4; m++) {
        #pragma unroll
        for (int n = 0; n < 4; n++) {
            #pragma unroll
            for (int jj = 0; jj < 4; jj++) {
                int gr = mt * 128 + wr * 64 + m * 16 + kq * 4 + jj;
                if (gr < cnt) {
                    float v = acc[m][n][jj];
                    if (SILU) v = v / (1.0f + __expf(-v));
                    int col = nt * 128 + wc * 64 + n * 16 + l15;
                    C[((size_t)sk * (T_TOK * 2) + off + gr) * N + col] = f2bf(v);
                }
            }
        }
    }
}

// ---------------- combine: out = residual + w0*sum_s y0_s + w1*sum_s y1_s ----------------
template<int SPLITS>
__global__ __launch_bounds__(256) void combine_kernel(
    const float* __restrict__ hs, const ushort* __restrict__ Yp,
    const float* __restrict__ topw, const int* __restrict__ tok_slot,
    float* __restrict__ out)
{
    int t = blockIdx.x, tid = threadIdx.x;
    int s0 = tok_slot[2 * t], s1 = tok_slot[2 * t + 1];
    float w0 = topw[2 * t], w1 = topw[2 * t + 1];
    const float* h = hs + (size_t)t * DM;
    float* o = out + (size_t)t * DM;
    #pragma unroll
    for (int i = 0; i < 3; i++) {
        int d = tid + i * 256;
        float y0 = 0.f, y1 = 0.f;
        #pragma unroll
        for (int s = 0; s < SPLITS; s++) {
            y0 += bf2f(Yp[((size_t)s * (T_TOK * 2) + s0) * DM + d]);
            y1 += bf2f(Yp[((size_t)s * (T_TOK * 2) + s1) * DM + d]);
        }
        o[d] = h[d] + w0 * y0 + w1 * y1;
    }
}

extern "C" void kernel_launch(void* const* d_in, const int* in_sizes, int n_in,
                              void* d_out, int out_size, void* d_ws, size_t ws_size,
                              hipStream_t stream)
{
    const float* hs    = (const float*)d_in[0];
    const float* gamma = (const float*)d_in[1];
    const float* beta  = (const float*)d_in[2];
    const float* rw    = (const float*)d_in[3];
    const float* w1    = (const float*)d_in[4];
    const float* w2    = (const float*)d_in[5];
    float* out = (float*)d_out;
    char* ws = (char*)d_ws;

    size_t o = 0;
    auto alc = [&](size_t b) { size_t r = o; o += (b + 255) & ~255ULL; return r; };
    int*      ctl        = (int*)(ws + alc(256));
    float*    topw       = (float*)(ws + alc((size_t)T_TOK * 2 * 4));
    int*      topi       = (int*)(ws + alc((size_t)T_TOK * 2 * 4));
    int*      tok_slot   = (int*)(ws + alc((size_t)T_TOK * 2 * 4));
    int*      bucket_tok = (int*)(ws + alc((size_t)T_TOK * 2 * 4));
    ushort*   xbf        = (ushort*)(ws + alc((size_t)T_TOK * DM * 2));
    ushort*   Hg         = (ushort*)(ws + alc((size_t)T_TOK * 2 * DF * 2));
    size_t yp_off        = alc((size_t)4 * T_TOK * 2 * DM * 2);
    ushort*   Yp         = (ushort*)(ws + yp_off);
    bool can_split       = (o <= ws_size);

    hipMemsetAsync(ctl, 0, 256, stream);
    ln_router_kernel<<<T_TOK, 256, 0, stream>>>(hs, gamma, beta, rw, xbf, topw, topi, ctl);
    bucket_kernel<<<8, 256, 0, stream>>>(topi, ctl, bucket_tok, tok_slot);

    moe_gemm<true, true, 24, 1><<<8 * 16 * 24, 256, 0, stream>>>(
        xbf, w1, Hg, ctl, bucket_tok, DM, DF);

    if (can_split) {
        moe_gemm<false, false, 6, 4><<<8 * 16 * 6 * 4, 256, 0, stream>>>(
            Hg, w2, Yp, ctl, bucket_tok, DF, DM);
        combine_kernel<4><<<T_TOK, 256, 0, stream>>>(hs, Yp, topw, tok_slot, out);
    } else {
        moe_gemm<false, false, 6, 1><<<8 * 16 * 6, 256, 0, stream>>>(
            Hg, w2, Yp, ctl, bucket_tok, DF, DM);
        combine_kernel<1><<<T_TOK, 256, 0, stream>>>(hs, Yp, topw, tok_slot, out);
    }
}

// Round 6
// 303.625 us; speedup vs baseline: 1.3010x; 1.3010x over previous
//
#include <hip/hip_runtime.h>
#include <hip/hip_bf16.h>
#include <math.h>

#define T_TOK 2048
#define DM 768
#define DF 3072
#define NE 8

typedef __attribute__((ext_vector_type(4))) float f32x4;
typedef __attribute__((ext_vector_type(8))) short bf16x8;

static __device__ __forceinline__ ushort f2bf(float f) {
    union { float f; unsigned u; } x; x.f = f;
    unsigned r = x.u + 0x7fff + ((x.u >> 16) & 1);
    return (ushort)(r >> 16);
}
static __device__ __forceinline__ float bf2f(ushort u) {
    union { unsigned u; float f; } x; x.u = ((unsigned)u) << 16; return x.f;
}
static __device__ __forceinline__ unsigned pk2(float lo, float hi) {
    return (unsigned)f2bf(lo) | ((unsigned)f2bf(hi) << 16);
}

// ---------------- LN + router (top-2) ----------------
__global__ __launch_bounds__(256) void ln_router_kernel(
    const float* __restrict__ hs, const float* __restrict__ gamma,
    const float* __restrict__ beta, const float* __restrict__ rw,
    ushort* __restrict__ xbf, float* __restrict__ topw, int* __restrict__ topi,
    int* __restrict__ counts)
{
    int t = blockIdx.x;
    int tid = threadIdx.x;
    const float* row = hs + (size_t)t * DM;
    float v[3];
    v[0] = row[tid]; v[1] = row[tid + 256]; v[2] = row[tid + 512];
    float s  = v[0] + v[1] + v[2];
    float sq = v[0]*v[0] + v[1]*v[1] + v[2]*v[2];
    #pragma unroll
    for (int off = 32; off > 0; off >>= 1) {
        s  += __shfl_down(s, off);
        sq += __shfl_down(sq, off);
    }
    __shared__ float wsum[4], wsq[4];
    __shared__ float pl[4][8];
    int lane = tid & 63, wv = tid >> 6;
    if (lane == 0) { wsum[wv] = s; wsq[wv] = sq; }
    __syncthreads();
    float tot  = wsum[0] + wsum[1] + wsum[2] + wsum[3];
    float totq = wsq[0] + wsq[1] + wsq[2] + wsq[3];
    float mu = tot * (1.0f / 768.0f);
    float var = totq * (1.0f / 768.0f) - mu * mu;
    float rstd = rsqrtf(var + 1e-5f);

    float p[8];
    #pragma unroll
    for (int e = 0; e < 8; e++) p[e] = 0.f;
    #pragma unroll
    for (int i = 0; i < 3; i++) {
        int d = tid + i * 256;
        float yv = (v[i] - mu) * rstd * gamma[d] + beta[d];
        xbf[(size_t)t * DM + d] = f2bf(yv);
        const float* r8 = rw + (size_t)d * 8;
        #pragma unroll
        for (int e = 0; e < 8; e++) p[e] += yv * r8[e];
    }
    #pragma unroll
    for (int off = 32; off > 0; off >>= 1) {
        #pragma unroll
        for (int e = 0; e < 8; e++) p[e] += __shfl_down(p[e], off);
    }
    if (lane == 0) {
        #pragma unroll
        for (int e = 0; e < 8; e++) pl[wv][e] = p[e];
    }
    __syncthreads();
    if (tid == 0) {
        float lg[8];
        #pragma unroll
        for (int e = 0; e < 8; e++) lg[e] = pl[0][e] + pl[1][e] + pl[2][e] + pl[3][e];
        int i0 = 0; float l0 = lg[0];
        #pragma unroll
        for (int e = 1; e < 8; e++) if (lg[e] > l0) { l0 = lg[e]; i0 = e; }
        int i1 = -1; float l1 = -3.4e38f;
        #pragma unroll
        for (int e = 0; e < 8; e++) if (e != i0 && lg[e] > l1) { l1 = lg[e]; i1 = e; }
        float w0 = 1.0f / (1.0f + __expf(l1 - l0));
        topi[2 * t] = i0;  topi[2 * t + 1] = i1;
        topw[2 * t] = w0;  topw[2 * t + 1] = 1.0f - w0;
        atomicAdd(&counts[i0], 1);
        atomicAdd(&counts[i1], 1);
    }
}

// ---------------- bucket fill (offsets computed in-register) ----------------
__global__ __launch_bounds__(256) void bucket_kernel(
    const int* __restrict__ topi, int* __restrict__ ctl,
    int* __restrict__ bucket_tok, int* __restrict__ tok_slot)
{
    int t = blockIdx.x * 256 + threadIdx.x;
    if (t >= T_TOK) return;
    int offs[8]; int acc = 0;
    #pragma unroll
    for (int e = 0; e < 8; e++) { offs[e] = acc; acc += ctl[e]; }
    #pragma unroll
    for (int k = 0; k < 2; k++) {
        int e = topi[2 * t + k];
        int pos = atomicAdd(&ctl[16 + e], 1);
        int idx = offs[e] + pos;
        bucket_tok[idx] = t;
        tok_slot[2 * t + k] = idx;
    }
}

// ---------------- bucketed MFMA GEMM, fused fp32->bf16 convert ----------------
// C[M,N] = A[M,K] * W[K,N];  A: [M][K] bf16;  W: fp32 [E][K][N].
// 128x128 tile, BK=32, 4 waves. LDS 2-deep (32 KiB). A: global_load_lds depth-1,
// source-swizzled k-chunks (conflict-free reads). B: fp32 global->reg (DEPTH-2,
// double-buffered regs) -> pk2 -> swizzled ds_write. Counted vmcnt(4) before the
// barrier: drains A(t+1) only, leaves B(t+2) loads in flight across the barrier.
template<bool SILU, bool GATHER, int NT, int SPLITS>
__global__ __launch_bounds__(256) void moe_gemm(
    const ushort* __restrict__ A, const float* __restrict__ W,
    ushort* __restrict__ C, const int* __restrict__ ctl,
    const int* __restrict__ bucket_tok, int K, int N)
{
    int bid = blockIdx.x;
    int e = bid & 7;
    int j = bid >> 3;
    int mt = j & 15;
    int c = j >> 4;
    int nt = c % NT;
    int sk = c / NT;
    int cnt = ctl[e];
    if (mt * 128 >= cnt) return;
    int off = 0;
    #pragma unroll
    for (int q = 0; q < 8; q++) if (q < e) off += ctl[q];
    const int Ks = K / SPLITS;
    const int kbase = sk * Ks;

    __shared__ ushort Al[2][128 * 32];
    __shared__ unsigned Bl[2][16 * 128];

    int tid = threadIdx.x, lane = tid & 63, wv = tid >> 6;
    // A source chunk swizzle: dest slot s (=lane&3) gets source chunk s ^ ((lane>>3)&3).
    int kchA = ((lane & 3) ^ ((lane >> 3) & 3)) * 8;

    const ushort* aptr[2];
    #pragma unroll
    for (int i = 0; i < 2; i++) {
        int r = i * 64 + wv * 16 + (lane >> 2);
        int gr = mt * 128 + r;
        if (gr >= cnt) gr = cnt - 1;
        if (GATHER) aptr[i] = A + (size_t)bucket_tok[off + gr] * K;
        else        aptr[i] = A + (size_t)(off + gr) * K;
    }

    const float* Wb = W + (size_t)e * ((size_t)K * N);
    int n0 = nt * 128;
    int rp_[2], cc_[2];
    #pragma unroll
    for (int ii = 0; ii < 2; ii++) {
        int item = wv * 128 + ii * 64 + lane;
        rp_[ii] = item >> 5;          // k-pair row 0..15
        cc_[ii] = item & 31;          // col chunk (4 u32)
    }

    f32x4 acc[4][4];
    #pragma unroll
    for (int m = 0; m < 4; m++)
        #pragma unroll
        for (int n = 0; n < 4; n++)
            acc[m][n] = (f32x4){0.f, 0.f, 0.f, 0.f};

    int wr = wv >> 1, wc = wv & 1;
    int l15 = lane & 15, kq = lane >> 4;
    int ldstA = (wv * 16) * 32 + lane * 8;
    int xk = (kq & 1) << 4;

    auto stageA = [&](int buf, int k0) {
        #pragma unroll
        for (int i = 0; i < 2; i++) {
            __builtin_amdgcn_global_load_lds(
                (const __attribute__((address_space(1))) void*)(aptr[i] + k0 + kchA),
                (__attribute__((address_space(3))) void*)(&Al[buf][i * 64 * 32 + ldstA]),
                16, 0, 0);
        }
    };
    auto bload = [&](float4 (&br)[2][2], int k0) {
        #pragma unroll
        for (int ii = 0; ii < 2; ii++) {
            const float* s = Wb + (size_t)(k0 + 2 * rp_[ii]) * N + n0 + 4 * cc_[ii];
            br[ii][0] = *(const float4*)s;
            br[ii][1] = *(const float4*)(s + N);
        }
    };
    auto bwrite = [&](float4 (&br)[2][2], int buf) {
        #pragma unroll
        for (int ii = 0; ii < 2; ii++) {
            uint4 r;
            r.x = pk2(br[ii][0].x, br[ii][1].x);
            r.y = pk2(br[ii][0].y, br[ii][1].y);
            r.z = pk2(br[ii][0].z, br[ii][1].z);
            r.w = pk2(br[ii][0].w, br[ii][1].w);
            *(uint4*)&Bl[buf][rp_[ii] * 128 + ((4 * cc_[ii]) ^ ((rp_[ii] & 7) << 2))] = r;
        }
    };
    auto compute = [&](int cur) {
        bf16x8 af[4], bfr[4];
        #pragma unroll
        for (int m = 0; m < 4; m++) {
            int row = wr * 64 + m * 16 + l15;
            af[m] = *(const bf16x8*)&Al[cur][row * 32 + ((kq ^ ((row >> 1) & 3)) << 3)];
        }
        const unsigned* Blc = &Bl[cur][0];
        #pragma unroll
        for (int n = 0; n < 4; n++) {
            int ncol = wc * 64 + n * 16 + l15;
            union { uint4 u; bf16x8 h; } cvu;
            cvu.u.x = Blc[(kq * 4 + 0) * 128 + (ncol ^ (xk | 0))];
            cvu.u.y = Blc[(kq * 4 + 1) * 128 + (ncol ^ (xk | 4))];
            cvu.u.z = Blc[(kq * 4 + 2) * 128 + (ncol ^ (xk | 8))];
            cvu.u.w = Blc[(kq * 4 + 3) * 128 + (ncol ^ (xk | 12))];
            bfr[n] = cvu.h;
        }
        __builtin_amdgcn_s_setprio(1);
        #pragma unroll
        for (int m = 0; m < 4; m++)
            #pragma unroll
            for (int n = 0; n < 4; n++)
                acc[m][n] = __builtin_amdgcn_mfma_f32_16x16x32_bf16(af[m], bfr[n], acc[m][n], 0, 0, 0);
        __builtin_amdgcn_s_setprio(0);
    };

    #define FENCE asm volatile("" ::: "memory")
    float4 brg0[2][2], brg1[2][2];
    const int nk = Ks >> 5;   // even (24 or 6) for our launches

    // prologue: A0 staged; B0,B1 reg-loaded; B0 written to LDS.
    stageA(0, kbase);
    bload(brg0, kbase);
    bload(brg1, kbase + 32);
    bwrite(brg0, 0);   // compiler-inserted wait drains A0+brg0 (oldest-first); brg1 stays in flight
    asm volatile("s_waitcnt lgkmcnt(0)" ::: "memory");
    __builtin_amdgcn_s_barrier();

    // iter t: stageA(t+1) [issued FIRST -> oldest], bload(t+2)->BLD, compute(t),
    //         bwrite(t+1)<-BWR, vmcnt(4) [drain A(t+1), keep B(t+2)], barrier.
    #define BODY(T, BLD, BWR) { \
        int t_ = (T); \
        if (t_ + 1 < nk) { stageA((t_ + 1) & 1, kbase + (t_ + 1) * 32); FENCE; } \
        if (t_ + 2 < nk) { bload(BLD, kbase + (t_ + 2) * 32); } \
        compute(t_ & 1); \
        if (t_ + 1 < nk) { \
            bwrite(BWR, (t_ + 1) & 1); \
            if (t_ + 2 < nk) asm volatile("s_waitcnt vmcnt(4)" ::: "memory"); \
            else             asm volatile("s_waitcnt vmcnt(0)" ::: "memory"); \
            asm volatile("s_waitcnt lgkmcnt(0)" ::: "memory"); \
            __builtin_amdgcn_s_barrier(); \
        } \
    }

    for (int t = 0; t < nk; t += 2) {
        BODY(t, brg0, brg1);
        BODY(t + 1, brg1, brg0);
    }
    #undef BODY
    #undef FENCE

    // epilogue: row = (lane>>4)*4 + jj, col = lane&15
    #pragma unroll
    for (int m = 0; m < 4; m++) {
        #pragma unroll
        for (int n = 0; n < 4; n++) {
            #pragma unroll
            for (int jj = 0; jj < 4; jj++) {
                int gr = mt * 128 + wr * 64 + m * 16 + kq * 4 + jj;
                if (gr < cnt) {
                    float v = acc[m][n][jj];
                    if (SILU) v = v / (1.0f + __expf(-v));
                    int col = nt * 128 + wc * 64 + n * 16 + l15;
                    C[((size_t)sk * (T_TOK * 2) + off + gr) * N + col] = f2bf(v);
                }
            }
        }
    }
}

// ---------------- combine: out = residual + w0*sum_s y0_s + w1*sum_s y1_s ----------------
template<int SPLITS>
__global__ __launch_bounds__(256) void combine_kernel(
    const float* __restrict__ hs, const ushort* __restrict__ Yp,
    const float* __restrict__ topw, const int* __restrict__ tok_slot,
    float* __restrict__ out)
{
    int t = blockIdx.x, tid = threadIdx.x;
    int s0 = tok_slot[2 * t], s1 = tok_slot[2 * t + 1];
    float w0 = topw[2 * t], w1 = topw[2 * t + 1];
    const float* h = hs + (size_t)t * DM;
    float* o = out + (size_t)t * DM;
    #pragma unroll
    for (int i = 0; i < 3; i++) {
        int d = tid + i * 256;
        float y0 = 0.f, y1 = 0.f;
        #pragma unroll
        for (int s = 0; s < SPLITS; s++) {
            y0 += bf2f(Yp[((size_t)s * (T_TOK * 2) + s0) * DM + d]);
            y1 += bf2f(Yp[((size_t)s * (T_TOK * 2) + s1) * DM + d]);
        }
        o[d] = h[d] + w0 * y0 + w1 * y1;
    }
}

extern "C" void kernel_launch(void* const* d_in, const int* in_sizes, int n_in,
                              void* d_out, int out_size, void* d_ws, size_t ws_size,
                              hipStream_t stream)
{
    const float* hs    = (const float*)d_in[0];
    const float* gamma = (const float*)d_in[1];
    const float* beta  = (const float*)d_in[2];
    const float* rw    = (const float*)d_in[3];
    const float* w1    = (const float*)d_in[4];
    const float* w2    = (const float*)d_in[5];
    float* out = (float*)d_out;
    char* ws = (char*)d_ws;

    size_t o = 0;
    auto alc = [&](size_t b) { size_t r = o; o += (b + 255) & ~255ULL; return r; };
    int*      ctl        = (int*)(ws + alc(256));
    float*    topw       = (float*)(ws + alc((size_t)T_TOK * 2 * 4));
    int*      topi       = (int*)(ws + alc((size_t)T_TOK * 2 * 4));
    int*      tok_slot   = (int*)(ws + alc((size_t)T_TOK * 2 * 4));
    int*      bucket_tok = (int*)(ws + alc((size_t)T_TOK * 2 * 4));
    ushort*   xbf        = (ushort*)(ws + alc((size_t)T_TOK * DM * 2));
    ushort*   Hg         = (ushort*)(ws + alc((size_t)T_TOK * 2 * DF * 2));
    size_t yp_off        = alc((size_t)4 * T_TOK * 2 * DM * 2);
    ushort*   Yp         = (ushort*)(ws + yp_off);
    bool can_split       = (o <= ws_size);

    hipMemsetAsync(ctl, 0, 256, stream);
    ln_router_kernel<<<T_TOK, 256, 0, stream>>>(hs, gamma, beta, rw, xbf, topw, topi, ctl);
    bucket_kernel<<<8, 256, 0, stream>>>(topi, ctl, bucket_tok, tok_slot);

    moe_gemm<true, true, 24, 1><<<8 * 16 * 24, 256, 0, stream>>>(
        xbf, w1, Hg, ctl, bucket_tok, DM, DF);

    if (can_split) {
        moe_gemm<false, false, 6, 4><<<8 * 16 * 6 * 4, 256, 0, stream>>>(
            Hg, w2, Yp, ctl, bucket_tok, DF, DM);
        combine_kernel<4><<<T_TOK, 256, 0, stream>>>(hs, Yp, topw, tok_slot, out);
    } else {
        moe_gemm<false, false, 6, 1><<<8 * 16 * 6, 256, 0, stream>>>(
            Hg, w2, Yp, ctl, bucket_tok, DF, DM);
        combine_kernel<1><<<T_TOK, 256, 0, stream>>>(hs, Yp, topw, tok_slot, out);
    }
}

// Round 7
// 214.299 us; speedup vs baseline: 1.8432x; 1.4168x over previous
//
#include <hip/hip_runtime.h>
#include <hip/hip_bf16.h>
#include <math.h>

#define T_TOK 2048
#define DM 768
#define DF 3072
#define NE 8
#define NTILES_MAX 40

typedef __attribute__((ext_vector_type(4))) float f32x4;
typedef __attribute__((ext_vector_type(8))) short bf16x8;

static __device__ __forceinline__ ushort f2bf(float f) {
    union { float f; unsigned u; } x; x.f = f;
    unsigned r = x.u + 0x7fff + ((x.u >> 16) & 1);
    return (ushort)(r >> 16);
}
static __device__ __forceinline__ float bf2f(ushort u) {
    union { unsigned u; float f; } x; x.u = ((unsigned)u) << 16; return x.f;
}
static __device__ __forceinline__ unsigned pk2(float lo, float hi) {
    unsigned r;
    asm("v_cvt_pk_bf16_f32 %0, %1, %2" : "=v"(r) : "v"(lo), "v"(hi));
    return r;
}

// ---------------- LN + router (top-2) ----------------
__global__ __launch_bounds__(256) void ln_router_kernel(
    const float* __restrict__ hs, const float* __restrict__ gamma,
    const float* __restrict__ beta, const float* __restrict__ rw,
    ushort* __restrict__ xbf, float* __restrict__ topw, int* __restrict__ topi,
    int* __restrict__ counts)
{
    int t = blockIdx.x;
    int tid = threadIdx.x;
    const float* row = hs + (size_t)t * DM;
    float v[3];
    v[0] = row[tid]; v[1] = row[tid + 256]; v[2] = row[tid + 512];
    float s  = v[0] + v[1] + v[2];
    float sq = v[0]*v[0] + v[1]*v[1] + v[2]*v[2];
    #pragma unroll
    for (int off = 32; off > 0; off >>= 1) {
        s  += __shfl_down(s, off);
        sq += __shfl_down(sq, off);
    }
    __shared__ float wsum[4], wsq[4];
    __shared__ float pl[4][8];
    int lane = tid & 63, wv = tid >> 6;
    if (lane == 0) { wsum[wv] = s; wsq[wv] = sq; }
    __syncthreads();
    float tot  = wsum[0] + wsum[1] + wsum[2] + wsum[3];
    float totq = wsq[0] + wsq[1] + wsq[2] + wsq[3];
    float mu = tot * (1.0f / 768.0f);
    float var = totq * (1.0f / 768.0f) - mu * mu;
    float rstd = rsqrtf(var + 1e-5f);

    float p[8];
    #pragma unroll
    for (int e = 0; e < 8; e++) p[e] = 0.f;
    #pragma unroll
    for (int i = 0; i < 3; i++) {
        int d = tid + i * 256;
        float yv = (v[i] - mu) * rstd * gamma[d] + beta[d];
        xbf[(size_t)t * DM + d] = f2bf(yv);
        const float* r8 = rw + (size_t)d * 8;
        #pragma unroll
        for (int e = 0; e < 8; e++) p[e] += yv * r8[e];
    }
    #pragma unroll
    for (int off = 32; off > 0; off >>= 1) {
        #pragma unroll
        for (int e = 0; e < 8; e++) p[e] += __shfl_down(p[e], off);
    }
    if (lane == 0) {
        #pragma unroll
        for (int e = 0; e < 8; e++) pl[wv][e] = p[e];
    }
    __syncthreads();
    if (tid == 0) {
        float lg[8];
        #pragma unroll
        for (int e = 0; e < 8; e++) lg[e] = pl[0][e] + pl[1][e] + pl[2][e] + pl[3][e];
        int i0 = 0; float l0 = lg[0];
        #pragma unroll
        for (int e = 1; e < 8; e++) if (lg[e] > l0) { l0 = lg[e]; i0 = e; }
        int i1 = -1; float l1 = -3.4e38f;
        #pragma unroll
        for (int e = 0; e < 8; e++) if (e != i0 && lg[e] > l1) { l1 = lg[e]; i1 = e; }
        float w0 = 1.0f / (1.0f + __expf(l1 - l0));
        topi[2 * t] = i0;  topi[2 * t + 1] = i1;
        topw[2 * t] = w0;  topw[2 * t + 1] = 1.0f - w0;
        atomicAdd(&counts[i0], 1);
        atomicAdd(&counts[i1], 1);
    }
}

// ---------------- scan: build tile table (every GEMM block will be active) ----------------
// ctl[0..7]=counts, [16..23]=cursors(zeroed by memset), [24]=ntiles
__global__ void scan_kernel(int* __restrict__ ctl, int4* __restrict__ tiles)
{
    if (threadIdx.x == 0 && blockIdx.x == 0) {
        int acc = 0, nt = 0;
        for (int e = 0; e < 8; e++) {
            int cnt = ctl[e];
            for (int m0 = 0; m0 < cnt; m0 += 128) {
                tiles[nt] = make_int4(e, acc + m0, min(128, cnt - m0), 0);
                nt++;
            }
            acc += cnt;
        }
        ctl[24] = nt;
    }
}

// ---------------- bucket fill (offsets computed in-register) ----------------
__global__ __launch_bounds__(256) void bucket_kernel(
    const int* __restrict__ topi, int* __restrict__ ctl,
    int* __restrict__ bucket_tok, int* __restrict__ tok_slot)
{
    int t = blockIdx.x * 256 + threadIdx.x;
    if (t >= T_TOK) return;
    int offs[8]; int acc = 0;
    #pragma unroll
    for (int e = 0; e < 8; e++) { offs[e] = acc; acc += ctl[e]; }
    #pragma unroll
    for (int k = 0; k < 2; k++) {
        int e = topi[2 * t + k];
        int pos = atomicAdd(&ctl[16 + e], 1);
        int idx = offs[e] + pos;
        bucket_tok[idx] = t;
        tok_slot[2 * t + k] = idx;
    }
}

// ---------------- bucketed MFMA GEMM, fused fp32->bf16 convert ----------------
// C[M,N] = A[M,K] * W[K,N];  A: [M][K] bf16;  W: fp32 [E][K][N].
// 128x128 tile, BK=32, 4 waves, round-4 schedule (depth-1 B regs, vmcnt(0) drains).
// Tile table: grid = NTILES_MAX * NT * SPLITS, block decodes (tile, nt, sk); all
// blocks with tl < ntiles are active. nt fastest => same-B-panel readers share XCD.
// A: global_load_lds with source k-chunk XOR swizzle (conflict-free frag reads).
// B: fp32 global->reg -> v_cvt_pk_bf16_f32 -> swizzled ds_write (u32 pairs [16][128]).
template<bool SILU, bool GATHER, int NT, int SPLITS>
__global__ __launch_bounds__(256) void moe_gemm(
    const ushort* __restrict__ A, const float* __restrict__ W,
    ushort* __restrict__ C, const int* __restrict__ ctl,
    const int* __restrict__ bucket_tok, const int4* __restrict__ tiles,
    int K, int N)
{
    int bid = blockIdx.x;
    int c  = bid % (NT * SPLITS);
    int tl = bid / (NT * SPLITS);
    if (tl >= ctl[24]) return;
    int nt = c % NT;
    int sk = c / NT;
    int4 t4 = tiles[tl];
    int e = t4.x, grow0 = t4.y, rows = t4.z;
    const int Ks = K / SPLITS;
    const int kbase = sk * Ks;

    __shared__ ushort Al[2][128 * 32];
    __shared__ unsigned Bl[2][16 * 128];

    int tid = threadIdx.x, lane = tid & 63, wv = tid >> 6;
    // A source chunk swizzle: dest slot s (=lane&3) takes source chunk s ^ ((lane>>3)&3).
    int kchA = ((lane & 3) ^ ((lane >> 3) & 3)) * 8;

    const ushort* aptr[2];
    #pragma unroll
    for (int i = 0; i < 2; i++) {
        int r = i * 64 + wv * 16 + (lane >> 2);
        int rr = r < rows ? r : rows - 1;
        if (GATHER) aptr[i] = A + (size_t)bucket_tok[grow0 + rr] * K;
        else        aptr[i] = A + (size_t)(grow0 + rr) * K;
    }

    const float* Wb = W + (size_t)e * ((size_t)K * N);
    int n0 = nt * 128;
    int rp_[2], cc_[2];
    #pragma unroll
    for (int ii = 0; ii < 2; ii++) {
        int item = wv * 128 + ii * 64 + lane;
        rp_[ii] = item >> 5;          // k-pair row 0..15
        cc_[ii] = item & 31;          // col chunk (4 u32)
    }

    f32x4 acc[4][4];
    #pragma unroll
    for (int m = 0; m < 4; m++)
        #pragma unroll
        for (int n = 0; n < 4; n++)
            acc[m][n] = (f32x4){0.f, 0.f, 0.f, 0.f};

    int wr = wv >> 1, wc = wv & 1;
    int l15 = lane & 15, kq = lane >> 4;
    int ldstA = (wv * 16) * 32 + lane * 8;
    int xk = (kq & 1) << 4;

    float4 brg[2][2];

    auto stageA = [&](int buf, int k0) {
        #pragma unroll
        for (int i = 0; i < 2; i++) {
            __builtin_amdgcn_global_load_lds(
                (const __attribute__((address_space(1))) void*)(aptr[i] + k0 + kchA),
                (__attribute__((address_space(3))) void*)(&Al[buf][i * 64 * 32 + ldstA]),
                16, 0, 0);
        }
    };
    auto bload = [&](int k0) {
        #pragma unroll
        for (int ii = 0; ii < 2; ii++) {
            const float* s = Wb + (size_t)(k0 + 2 * rp_[ii]) * N + n0 + 4 * cc_[ii];
            brg[ii][0] = *(const float4*)s;
            brg[ii][1] = *(const float4*)(s + N);
        }
    };
    auto bwrite = [&](int buf) {
        #pragma unroll
        for (int ii = 0; ii < 2; ii++) {
            uint4 r;
            r.x = pk2(brg[ii][0].x, brg[ii][1].x);
            r.y = pk2(brg[ii][0].y, brg[ii][1].y);
            r.z = pk2(brg[ii][0].z, brg[ii][1].z);
            r.w = pk2(brg[ii][0].w, brg[ii][1].w);
            *(uint4*)&Bl[buf][rp_[ii] * 128 + ((4 * cc_[ii]) ^ ((rp_[ii] & 7) << 2))] = r;
        }
    };
    auto compute = [&](int cur) {
        bf16x8 af[4], bfr[4];
        #pragma unroll
        for (int m = 0; m < 4; m++) {
            int row = wr * 64 + m * 16 + l15;
            af[m] = *(const bf16x8*)&Al[cur][row * 32 + ((kq ^ ((row >> 1) & 3)) << 3)];
        }
        const unsigned* Blc = &Bl[cur][0];
        #pragma unroll
        for (int n = 0; n < 4; n++) {
            int ncol = wc * 64 + n * 16 + l15;
            union { uint4 u; bf16x8 h; } cvu;
            cvu.u.x = Blc[(kq * 4 + 0) * 128 + (ncol ^ (xk | 0))];
            cvu.u.y = Blc[(kq * 4 + 1) * 128 + (ncol ^ (xk | 4))];
            cvu.u.z = Blc[(kq * 4 + 2) * 128 + (ncol ^ (xk | 8))];
            cvu.u.w = Blc[(kq * 4 + 3) * 128 + (ncol ^ (xk | 12))];
            bfr[n] = cvu.h;
        }
        __builtin_amdgcn_s_setprio(1);
        #pragma unroll
        for (int m = 0; m < 4; m++)
            #pragma unroll
            for (int n = 0; n < 4; n++)
                acc[m][n] = __builtin_amdgcn_mfma_f32_16x16x32_bf16(af[m], bfr[n], acc[m][n], 0, 0, 0);
        __builtin_amdgcn_s_setprio(0);
    };

    const int nk = Ks >> 5;
    stageA(0, kbase);
    bload(kbase);
    asm volatile("s_waitcnt vmcnt(0)" ::: "memory");
    bwrite(0);
    asm volatile("s_waitcnt lgkmcnt(0)" ::: "memory");
    __builtin_amdgcn_s_barrier();

    for (int ks = 0; ks < nk; ks++) {
        int cur = ks & 1;
        bool more = (ks + 1 < nk);
        if (more) {
            stageA(cur ^ 1, kbase + (ks + 1) * 32);
            bload(kbase + (ks + 1) * 32);
        }
        compute(cur);
        if (more) {
            asm volatile("s_waitcnt vmcnt(0)" ::: "memory");
            bwrite(cur ^ 1);
        }
        asm volatile("s_waitcnt vmcnt(0) lgkmcnt(0)" ::: "memory");
        __builtin_amdgcn_s_barrier();
    }

    // epilogue: row = (lane>>4)*4 + jj, col = lane&15
    #pragma unroll
    for (int m = 0; m < 4; m++) {
        #pragma unroll
        for (int n = 0; n < 4; n++) {
            #pragma unroll
            for (int jj = 0; jj < 4; jj++) {
                int r = wr * 64 + m * 16 + kq * 4 + jj;
                if (r < rows) {
                    float v = acc[m][n][jj];
                    if (SILU) v = v / (1.0f + __expf(-v));
                    int col = nt * 128 + wc * 64 + n * 16 + l15;
                    C[((size_t)sk * (T_TOK * 2) + grow0 + r) * N + col] = f2bf(v);
                }
            }
        }
    }
}

// ---------------- combine: out = residual + w0*sum_s y0_s + w1*sum_s y1_s ----------------
template<int SPLITS>
__global__ __launch_bounds__(256) void combine_kernel(
    const float* __restrict__ hs, const ushort* __restrict__ Yp,
    const float* __restrict__ topw, const int* __restrict__ tok_slot,
    float* __restrict__ out)
{
    int t = blockIdx.x, tid = threadIdx.x;
    int s0 = tok_slot[2 * t], s1 = tok_slot[2 * t + 1];
    float w0 = topw[2 * t], w1 = topw[2 * t + 1];
    const float* h = hs + (size_t)t * DM;
    float* o = out + (size_t)t * DM;
    #pragma unroll
    for (int i = 0; i < 3; i++) {
        int d = tid + i * 256;
        float y0 = 0.f, y1 = 0.f;
        #pragma unroll
        for (int s = 0; s < SPLITS; s++) {
            y0 += bf2f(Yp[((size_t)s * (T_TOK * 2) + s0) * DM + d]);
            y1 += bf2f(Yp[((size_t)s * (T_TOK * 2) + s1) * DM + d]);
        }
        o[d] = h[d] + w0 * y0 + w1 * y1;
    }
}

extern "C" void kernel_launch(void* const* d_in, const int* in_sizes, int n_in,
                              void* d_out, int out_size, void* d_ws, size_t ws_size,
                              hipStream_t stream)
{
    const float* hs    = (const float*)d_in[0];
    const float* gamma = (const float*)d_in[1];
    const float* beta  = (const float*)d_in[2];
    const float* rw    = (const float*)d_in[3];
    const float* w1    = (const float*)d_in[4];
    const float* w2    = (const float*)d_in[5];
    float* out = (float*)d_out;
    char* ws = (char*)d_ws;

    size_t o = 0;
    auto alc = [&](size_t b) { size_t r = o; o += (b + 255) & ~255ULL; return r; };
    int*      ctl        = (int*)(ws + alc(256));
    int4*     tiles      = (int4*)(ws + alc(NTILES_MAX * 16));
    float*    topw       = (float*)(ws + alc((size_t)T_TOK * 2 * 4));
    int*      topi       = (int*)(ws + alc((size_t)T_TOK * 2 * 4));
    int*      tok_slot   = (int*)(ws + alc((size_t)T_TOK * 2 * 4));
    int*      bucket_tok = (int*)(ws + alc((size_t)T_TOK * 2 * 4));
    ushort*   xbf        = (ushort*)(ws + alc((size_t)T_TOK * DM * 2));
    ushort*   Hg         = (ushort*)(ws + alc((size_t)T_TOK * 2 * DF * 2));
    size_t yp_off        = alc((size_t)4 * T_TOK * 2 * DM * 2);
    ushort*   Yp         = (ushort*)(ws + yp_off);
    bool can_split       = (o <= ws_size);

    hipMemsetAsync(ctl, 0, 256, stream);
    ln_router_kernel<<<T_TOK, 256, 0, stream>>>(hs, gamma, beta, rw, xbf, topw, topi, ctl);
    scan_kernel<<<1, 64, 0, stream>>>(ctl, tiles);
    bucket_kernel<<<8, 256, 0, stream>>>(topi, ctl, bucket_tok, tok_slot);

    moe_gemm<true, true, 24, 1><<<NTILES_MAX * 24, 256, 0, stream>>>(
        xbf, w1, Hg, ctl, bucket_tok, tiles, DM, DF);

    if (can_split) {
        moe_gemm<false, false, 6, 4><<<NTILES_MAX * 6 * 4, 256, 0, stream>>>(
            Hg, w2, Yp, ctl, bucket_tok, tiles, DF, DM);
        combine_kernel<4><<<T_TOK, 256, 0, stream>>>(hs, Yp, topw, tok_slot, out);
    } else {
        moe_gemm<false, false, 6, 1><<<NTILES_MAX * 6, 256, 0, stream>>>(
            Hg, w2, Yp, ctl, bucket_tok, tiles, DF, DM);
        combine_kernel<1><<<T_TOK, 256, 0, stream>>>(hs, Yp, topw, tok_slot, out);
    }
}